// Round 7
// baseline (10466.775 us; speedup 1.0000x reference)
//
#include <hip/hip_runtime.h>

// Problem constants (from reference setup_inputs)
#define BATCH    16
#define NPTS     32768
#define NPOINT   2048
#define C_FEAT   128

#define NTHREADS 1024
#define PPT      (NPTS / NTHREADS)   // 32 points per thread
#define NWAVES   (NTHREADS / 64)     // 16 waves per block

// ===========================================================================
// ROUND 7: test the FMA-CONTRACTED distance pipeline (the one 1-ulp-class
// variant never actually tested -- r1's __f*_rn DID block contraction, so
// r1/r3/r4/r5 were all plain f32 and r2 was f64; all five shared one
// trajectory). Round-6 probe showed: layout/gather correct, mismatches are
// rare flips (close-pair 0.0625 event in first half, 1.52 event in second),
// i.e. the refs share a 1-ulp-different arithmetic that flips rare near-ties.
// Canonical contraction of ((dx^2+dy^2)+dz^2):
//     d = fmaf(dz, dz, fmaf(dy, dy, dx*dx))
// Everything else bit-identical to round 5 (two-pass exact argmax).
// ===========================================================================

__global__ __launch_bounds__(NTHREADS) void fps_kernel(
    const float* __restrict__ xyz, int* __restrict__ fps_idx) {
  const int b = blockIdx.x;
  const int t = threadIdx.x;
  const float* __restrict__ base = xyz + (size_t)b * NPTS * 3;

  __shared__ float s_wmax[NWAVES];
  __shared__ int   s_widx[NWAVES];
  __shared__ int   s_far;

  float dmin[PPT];
#pragma unroll
  for (int k = 0; k < PPT; ++k) dmin[k] = 1e10f;

  int far = 0;  // deterministic start at index 0 (matches reference)

  for (int s = 0; s < NPOINT; ++s) {
    if (t == 0) fps_idx[b * NPOINT + s] = far;

    const float cx = base[(size_t)far * 3 + 0];
    const float cy = base[(size_t)far * 3 + 1];
    const float cz = base[(size_t)far * 3 + 2];

    // ---- update running min; track local max VALUE only ----
    float vmax = -1.0f;
#pragma unroll
    for (int k = 0; k < PPT; ++k) {
      const int p = t + k * NTHREADS;  // strided -> coalesced wave loads
      const float* __restrict__ q = base + (size_t)p * 3;
      const float dx = q[0] - cx;
      const float dy = q[1] - cy;
      const float dz = q[2] - cz;
      // FMA-contracted pipeline under test:
      const float d = __builtin_fmaf(dz, dz,
                        __builtin_fmaf(dy, dy, dx * dx));
      const float nd = fminf(dmin[k], d);
      dmin[k] = nd;
      vmax = fmaxf(vmax, nd);
    }

    // ---- pass 1: block-wide max value ----
#pragma unroll
    for (int off = 32; off > 0; off >>= 1)
      vmax = fmaxf(vmax, __shfl_xor(vmax, off));
    if ((t & 63) == 0) s_wmax[t >> 6] = vmax;
    __syncthreads();
    float M = s_wmax[0];
#pragma unroll
    for (int w = 1; w < NWAVES; ++w) M = fmaxf(M, s_wmax[w]);

    // ---- pass 2: smallest global index with dmin == M (first occurrence) ----
    int ilo = 0x7fffffff;
#pragma unroll
    for (int k = 0; k < PPT; ++k) {
      const int p = t + k * NTHREADS;
      if (dmin[k] == M && p < ilo) ilo = p;
    }
#pragma unroll
    for (int off = 32; off > 0; off >>= 1) {
      const int oi = __shfl_xor(ilo, off);
      ilo = (oi < ilo) ? oi : ilo;
    }
    if ((t & 63) == 0) s_widx[t >> 6] = ilo;
    __syncthreads();
    if (t == 0) {
      int bi = s_widx[0];
#pragma unroll
      for (int w = 1; w < NWAVES; ++w) bi = (s_widx[w] < bi) ? s_widx[w] : bi;
      s_far = bi;
    }
    __syncthreads();
    far = s_far;
  }
}

__global__ __launch_bounds__(256) void gather_kernel(
    const float* __restrict__ xyz, const float* __restrict__ feat,
    const int* __restrict__ fps_idx, float* __restrict__ out) {
  const int lane = threadIdx.x & 31;
  const int sub  = threadIdx.x >> 5;
  const int row  = blockIdx.x * 8 + sub;       // [0, BATCH*NPOINT)
  const int b    = row >> 11;                  // NPOINT == 2048
  const int src  = fps_idx[row];

  const float4* __restrict__ f =
      reinterpret_cast<const float4*>(feat + ((size_t)b * NPTS + src) * C_FEAT);
  float4* __restrict__ o =
      reinterpret_cast<float4*>(out + (size_t)BATCH * NPOINT * 3 +
                                (size_t)row * C_FEAT);
  o[lane] = f[lane];

  if (lane < 3) {
    out[(size_t)row * 3 + lane] = xyz[((size_t)b * NPTS + src) * 3 + lane];
  }
}

extern "C" void kernel_launch(void* const* d_in, const int* in_sizes, int n_in,
                              void* d_out, int out_size, void* d_ws, size_t ws_size,
                              hipStream_t stream) {
  (void)in_sizes; (void)n_in; (void)out_size; (void)ws_size;
  const float* xyz  = (const float*)d_in[0];
  const float* feat = (const float*)d_in[1];
  int*   fps_idx = (int*)d_ws;               // BATCH*NPOINT*4 = 128KB scratch
  float* out     = (float*)d_out;

  fps_kernel<<<BATCH, NTHREADS, 0, stream>>>(xyz, fps_idx);
  gather_kernel<<<(BATCH * NPOINT) / 8, 256, 0, stream>>>(xyz, feat, fps_idx, out);
}